// Round 1
// baseline (42.316 us; speedup 1.0000x reference)
//
#include <hip/hip_runtime.h>
#include <hip/hip_bf16.h>

// Problem constants (from the reference):
//   B=256, N=16384, D=7, NUM_CLASSES=3, EPS=1e-6
// Inputs (float32): output [B,N,7], target [B,N,7]. Output: scalar float32.

#define RB 256
#define RN 16384
#define RD 7
#define NREC (RB * RN)          // 4,194,304 records
#define BLOCK 256
#define GRID 2048               // 8 iterations per block, exact

__global__ __launch_bounds__(BLOCK) void loss_partial_kernel(
    const float* __restrict__ out, const float* __restrict__ tgt,
    float* __restrict__ partial) {
    __shared__ float so[BLOCK * RD];
    __shared__ float st[BLOCK * RD];

    float acc = 0.0f;
    const int t = threadIdx.x;

    for (int base = blockIdx.x * BLOCK; base < NREC; base += GRID * BLOCK) {
        // Stage 256 records (1792 floats each tensor) with fully coalesced loads.
        const int gbase = base * RD;
        __syncthreads();  // protect LDS from previous iteration's readers
#pragma unroll
        for (int k = 0; k < RD; ++k) {
            so[k * BLOCK + t] = out[gbase + k * BLOCK + t];
            st[k * BLOCK + t] = tgt[gbase + k * BLOCK + t];
        }
        __syncthreads();

        // Each thread processes one record. Stride-7 LDS read: gcd(7,32)=1 ->
        // conflict-free within 32 lanes; lanes r and r+32 alias 2-way (free).
        const float* ro = &so[t * RD];
        const float* rt = &st[t * RD];

        const float p_obj = ro[0];
        const float px = ro[1], py = ro[2], ps = ro[3];
        const float l0 = ro[4], l1 = ro[5], l2 = ro[6];
        const float t_obj = rt[0];
        const float tx = rt[1], ty = rt[2], ts = rt[3];
        const float cls = rt[4];

        const float m = (t_obj > 0.5f) ? 1.0f : 0.0f;

        // box regression
        const float dx = tx - px, dy = ty - py;
        const float dsz = __fsqrt_rn(ts) - __fsqrt_rn(ps);
        const float box = dx * dx + dy * dy + 2.0f * dsz * dsz;

        // IoU of axis-aligned squares
        const float hp = 0.5f * ps, ht = 0.5f * ts;
        const float lx = fmaxf(px - hp, tx - ht);
        const float rx = fminf(px + hp, tx + ht);
        const float ly = fmaxf(py - hp, ty - ht);
        const float ry = fminf(py + hp, ty + ht);
        const float inter = fmaxf(rx - lx, 0.0f) * fmaxf(ry - ly, 0.0f);
        const float uni = ps * ps + ts * ts - inter;
        const float iou = inter / (uni + 1e-6f);

        // shared log terms (p_obj in (0.01,0.99) so both logs are safe)
        const float logp  = __logf(p_obj);
        const float log1p = __logf(1.0f - p_obj);

        const float bce_obj = -(iou * logp + (1.0f - iou) * log1p);

        // 3-class log-softmax CE
        const float mx = fmaxf(fmaxf(l0, l1), l2);
        const float esum = __expf(l0 - mx) + __expf(l1 - mx) + __expf(l2 - mx);
        const float lse = mx + __logf(esum);
        const float lcls = (cls < 0.5f) ? l0 : ((cls < 1.5f) ? l1 : l2);
        const float ce = lse - lcls;

        const float bce_noobj = -(t_obj * logp + (1.0f - t_obj) * log1p);

        acc += m * (5.0f * box + 2.0f * ce + bce_obj)
             + 1.5f * (1.0f - m) * bce_noobj;
    }

    // wave reduce (64 lanes)
#pragma unroll
    for (int off = 32; off > 0; off >>= 1) acc += __shfl_down(acc, off);

    __shared__ float wsum[BLOCK / 64];
    if ((t & 63) == 0) wsum[t >> 6] = acc;
    __syncthreads();
    if (t == 0) {
        float s = 0.0f;
#pragma unroll
        for (int w = 0; w < BLOCK / 64; ++w) s += wsum[w];
        partial[blockIdx.x] = s;
    }
}

__global__ __launch_bounds__(BLOCK) void reduce_final_kernel(
    const float* __restrict__ partial, float* __restrict__ outp, int n) {
    float a = 0.0f;
    for (int i = threadIdx.x; i < n; i += BLOCK) a += partial[i];
#pragma unroll
    for (int off = 32; off > 0; off >>= 1) a += __shfl_down(a, off);
    __shared__ float wsum[BLOCK / 64];
    if ((threadIdx.x & 63) == 0) wsum[threadIdx.x >> 6] = a;
    __syncthreads();
    if (threadIdx.x == 0) {
        float s = 0.0f;
#pragma unroll
        for (int w = 0; w < BLOCK / 64; ++w) s += wsum[w];
        outp[0] = s;
    }
}

extern "C" void kernel_launch(void* const* d_in, const int* in_sizes, int n_in,
                              void* d_out, int out_size, void* d_ws, size_t ws_size,
                              hipStream_t stream) {
    const float* out = (const float*)d_in[0];  // output [B,N,7]
    const float* tgt = (const float*)d_in[1];  // target [B,N,7]
    float* partial = (float*)d_ws;             // GRID floats of scratch
    float* result = (float*)d_out;

    loss_partial_kernel<<<GRID, BLOCK, 0, stream>>>(out, tgt, partial);
    reduce_final_kernel<<<1, BLOCK, 0, stream>>>(partial, result, GRID);
}